// Round 4
// baseline (4729.928 us; speedup 1.0000x reference)
//
#include <hip/hip_runtime.h>
#include <hip/hip_bf16.h>
#include <hip/hip_cooperative_groups.h>
#include <cstddef>

typedef short bf16x8 __attribute__((ext_vector_type(8)));
typedef float f32x4 __attribute__((ext_vector_type(4)));

// Constants for this problem: V=4096, D=1024, H=1024, B=64, T=512

__device__ __forceinline__ short bf16rne(float f) {
  unsigned u = __builtin_bit_cast(unsigned, f);
  u += 0x7fffu + ((u >> 16) & 1u);
  return (short)(u >> 16);
}

// ---------------- K0a: elementwise f32 -> bf16 convert (x4 per thread) ----------------
__global__ void conv_f32_bf16_x4(const float* __restrict__ src, short* __restrict__ dst, int n4) {
  int i = blockIdx.x * blockDim.x + threadIdx.x;
  if (i >= n4) return;
  float4 v = ((const float4*)src)[i];
  unsigned long long o =
      (unsigned long long)(unsigned short)bf16rne(v.x) |
      ((unsigned long long)(unsigned short)bf16rne(v.y) << 16) |
      ((unsigned long long)(unsigned short)bf16rne(v.z) << 32) |
      ((unsigned long long)(unsigned short)bf16rne(v.w) << 48);
  ((unsigned long long*)dst)[i] = o;
}

// ---------------- K0b: tiled transpose + convert: dst[c][r] = bf16(src[r][c]) ----------------
__global__ void transpose_conv(const float* __restrict__ src, short* __restrict__ dst,
                               int R, int C) {
  __shared__ float tile[32][33];
  int tx = threadIdx.x, ty = threadIdx.y;
  int bx = blockIdx.x, by = blockIdx.y;
#pragma unroll
  for (int i = 0; i < 4; ++i)
    tile[ty + i * 8][tx] = src[(size_t)(by * 32 + ty + i * 8) * C + bx * 32 + tx];
  __syncthreads();
#pragma unroll
  for (int i = 0; i < 4; ++i)
    dst[(size_t)(bx * 32 + ty + i * 8) * R + by * 32 + tx] = bf16rne(tile[tx][ty + i * 8]);
}

// ---------------- K1/K3: 128x128 tile MFMA GEMM, BK=32, 4 waves (2x2 of 64x64) ----------------
template <bool GATHER, bool OUT_BF16>
__global__ __launch_bounds__(256) void gemm_bf16(
    const short* __restrict__ Abase, const int* __restrict__ gidx,
    const short* __restrict__ BT, const float* __restrict__ bias,
    void* __restrict__ Cout, int M, int N, int K) {
  __shared__ short As[128][40];
  __shared__ short Bs[128][40];
  const int tid = threadIdx.x;
  const int lane = tid & 63;
  const int wave = tid >> 6;
  const int mbase = blockIdx.x * 128;
  const int nbase = blockIdx.y * 128;
  const int wr = (wave >> 1) * 64;
  const int wc = (wave & 1) * 64;
  const int l15 = lane & 15;
  const int lk8 = (lane >> 4) * 8;
  const int r0 = tid >> 2;
  const int kc = (tid & 3) * 8;

  f32x4 acc[4][4] = {};

  for (int k0 = 0; k0 < K; k0 += 32) {
#pragma unroll
    for (int h = 0; h < 2; ++h) {
      int r = r0 + h * 64;
      size_t arow;
      if (GATHER) arow = (size_t)gidx[mbase + r];
      else        arow = (size_t)(mbase + r);
      *(bf16x8*)&As[r][kc] = *(const bf16x8*)(Abase + arow * (size_t)K + k0 + kc);
      *(bf16x8*)&Bs[r][kc] = *(const bf16x8*)(BT + (size_t)(nbase + r) * K + k0 + kc);
    }
    __syncthreads();
    bf16x8 af[4], bfr[4];
#pragma unroll
    for (int i = 0; i < 4; ++i) {
      af[i]  = *(const bf16x8*)&As[wr + i * 16 + l15][lk8];
      bfr[i] = *(const bf16x8*)&Bs[wc + i * 16 + l15][lk8];
    }
#pragma unroll
    for (int i = 0; i < 4; ++i)
#pragma unroll
      for (int j = 0; j < 4; ++j)
        acc[i][j] = __builtin_amdgcn_mfma_f32_16x16x32_bf16(af[i], bfr[j], acc[i][j], 0, 0, 0);
    __syncthreads();
  }

#pragma unroll
  for (int i = 0; i < 4; ++i)
#pragma unroll
    for (int j = 0; j < 4; ++j) {
      int col = nbase + wc + j * 16 + l15;
      float bv = bias ? bias[col] : 0.f;
#pragma unroll
      for (int r = 0; r < 4; ++r) {
        int row = mbase + wr + i * 16 + (lane >> 4) * 4 + r;
        float v = acc[i][j][r] + bv;
        if (OUT_BF16) ((short*)Cout)[(size_t)row * N + col] = bf16rne(v);
        else          ((float*)Cout)[(size_t)row * N + col] = v;
      }
    }
}

// ---------------- K2: recurrence; sc1 write-through stores + buffer_inv acquire ----------------
// 64 blocks x 256 threads; rg = bid>>4 owns batches [rg*16, rg*16+16); the 16
// col-blocks of a rowgroup sync via a monotone IF-resident counter.
// h stores are relaxed agent-scope (write through L2 to Infinity Cache); the
// acquire side is one buffer_inv per wave — no buffer_wbl2 anywhere.
__global__ __launch_bounds__(256, 1) void rnn_recur(
    const float* __restrict__ xp, const short* __restrict__ WrT,
    const float* __restrict__ h0, short* __restrict__ hs,
    unsigned int* __restrict__ bar) {
  const int tid = threadIdx.x;
  const int lane = tid & 63;
  const int wave = tid >> 6;
  const int bid = blockIdx.x;
  const int rg = bid >> 4;
  const int rowbase = rg * 16;
  const int colbase = (bid & 15) * 64 + wave * 16;
  const int l15 = lane & 15;
  const int lk8 = (lane >> 4) * 8;
  const int col = colbase + l15;
  unsigned int* cnt = bar + rg * 256;  // 1 KB apart per rowgroup

  // Preload Wr B-fragments for this wave's 16 columns (32 x bf16x8 = 128 VGPRs).
  bf16x8 wfrag[32];
#pragma unroll
  for (int ks = 0; ks < 32; ++ks)
    wfrag[ks] = *(const bf16x8*)(WrT + (size_t)col * 1024 + ks * 32 + lk8);

  const int rquad = (lane >> 4) * 4;  // first of this thread's 4 output rows

  // ---- t = 0: previous h is h0 (broadcast row) ----
  {
    f32x4 a0 = {}, a1 = {}, a2 = {}, a3 = {};
#pragma unroll
    for (int ks = 0; ks < 32; ks += 4) {
      bf16x8 a[4];
#pragma unroll
      for (int q = 0; q < 4; ++q) {
        const float* hp = h0 + (ks + q) * 32 + lk8;
#pragma unroll
        for (int j = 0; j < 8; ++j) a[q][j] = bf16rne(hp[j]);
      }
      a0 = __builtin_amdgcn_mfma_f32_16x16x32_bf16(a[0], wfrag[ks + 0], a0, 0, 0, 0);
      a1 = __builtin_amdgcn_mfma_f32_16x16x32_bf16(a[1], wfrag[ks + 1], a1, 0, 0, 0);
      a2 = __builtin_amdgcn_mfma_f32_16x16x32_bf16(a[2], wfrag[ks + 2], a2, 0, 0, 0);
      a3 = __builtin_amdgcn_mfma_f32_16x16x32_bf16(a[3], wfrag[ks + 3], a3, 0, 0, 0);
    }
    f32x4 acc = (a0 + a1) + (a2 + a3);
#pragma unroll
    for (int r = 0; r < 4; ++r) {
      int b = rowbase + rquad + r;
      size_t off = ((size_t)b * 512 + 0) * 1024 + col;
      short hv = bf16rne(tanhf(acc[r] + xp[off]));
      __hip_atomic_store(&hs[off], hv, __ATOMIC_RELAXED, __HIP_MEMORY_SCOPE_AGENT);
    }
  }

  // prefetch xp for t = 1
  float xv[4];
#pragma unroll
  for (int r = 0; r < 4; ++r)
    xv[r] = xp[((size_t)(rowbase + rquad + r) * 512 + 1) * 1024 + col];

  for (int t = 1; t < 512; ++t) {
    // keep wfrag live in VGPRs across the whole loop (prevent remat/reload)
#pragma unroll
    for (int ks = 0; ks < 32; ++ks) asm volatile("" : "+v"(wfrag[ks]));

    // prefetch xp for t+1 (static data — safe to read pre-barrier)
    const int tn = (t + 1 < 512) ? (t + 1) : 511;
    float xn[4];
#pragma unroll
    for (int r = 0; r < 4; ++r)
      xn[r] = xp[((size_t)(rowbase + rquad + r) * 512 + tn) * 1024 + col];

    // release: drain this wave's sc1 h-stores (now at IF), then block-wide join
    asm volatile("s_waitcnt vmcnt(0)" ::: "memory");
    __syncthreads();
    if (tid == 0) atomicAdd(cnt, 1u);

    // spin until all 16 blocks of this rowgroup posted h_{t-1}
    const unsigned target = 16u * (unsigned)t;
    while (__hip_atomic_load(cnt, __ATOMIC_RELAXED, __HIP_MEMORY_SCOPE_AGENT) < target) {}

    // acquire: invalidate stale L1/L2 so cached h loads refill from IF
    asm volatile("buffer_inv sc1" ::: "memory");

    // h_{t-1} @ Wr with 4 independent accumulator chains
    f32x4 a0 = {}, a1 = {}, a2 = {}, a3 = {};
    const short* hrow = hs + ((size_t)(rowbase + l15) * 512 + (t - 1)) * 1024;
#pragma unroll
    for (int ks = 0; ks < 32; ks += 4) {
      bf16x8 a[4];
#pragma unroll
      for (int q = 0; q < 4; ++q)
        a[q] = *(const bf16x8*)(hrow + (ks + q) * 32 + lk8);
      a0 = __builtin_amdgcn_mfma_f32_16x16x32_bf16(a[0], wfrag[ks + 0], a0, 0, 0, 0);
      a1 = __builtin_amdgcn_mfma_f32_16x16x32_bf16(a[1], wfrag[ks + 1], a1, 0, 0, 0);
      a2 = __builtin_amdgcn_mfma_f32_16x16x32_bf16(a[2], wfrag[ks + 2], a2, 0, 0, 0);
      a3 = __builtin_amdgcn_mfma_f32_16x16x32_bf16(a[3], wfrag[ks + 3], a3, 0, 0, 0);
    }
    f32x4 acc = (a0 + a1) + (a2 + a3);

#pragma unroll
    for (int r = 0; r < 4; ++r) {
      int b = rowbase + rquad + r;
      size_t off = ((size_t)b * 512 + t) * 1024 + col;
      short hv = bf16rne(tanhf(acc[r] + xv[r]));
      __hip_atomic_store(&hs[off], hv, __ATOMIC_RELAXED, __HIP_MEMORY_SCOPE_AGENT);
    }
#pragma unroll
    for (int r = 0; r < 4; ++r) xv[r] = xn[r];
  }
}

// ---------------- launch ----------------
extern "C" void kernel_launch(void* const* d_in, const int* in_sizes, int n_in,
                              void* d_out, int out_size, void* d_ws, size_t ws_size,
                              hipStream_t stream) {
  const int*   input = (const int*)d_in[0];    // [B][T] = [64][512]
  const float* embed = (const float*)d_in[1];  // [V][D] = [4096][1024]
  const float* Wc    = (const float*)d_in[2];  // [D+H][H] = [2048][1024]
  const float* bc    = (const float*)d_in[3];  // [H]
  const float* h0    = (const float*)d_in[4];  // [1][H]
  const float* Wh    = (const float*)d_in[5];  // [H][V] = [1024][4096]
  const float* bh    = (const float*)d_in[6];  // [V]

  char* ws = (char*)d_ws;
  float* xp   = (float*)(ws + 0);            // 32768*1024 f32  = 134,217,728 B
  short* hs   = (short*)(ws + 134217728);    // 32768*1024 bf16 =  67,108,864 B
  short* embB = (short*)(ws + 201326592);    // 4096*1024 bf16  =   8,388,608 B
  short* WxT  = (short*)(ws + 209715200);    // 1024*1024 bf16  =   2,097,152 B
  short* WrT  = (short*)(ws + 211812352);    // 1024*1024 bf16  =   2,097,152 B
  short* WhT  = (short*)(ws + 213909504);    // 4096*1024 bf16  =   8,388,608 B
  unsigned int* bar = (unsigned int*)(ws + 222298112);  // 4 KB barrier counters

  hipMemsetAsync(bar, 0, 4096, stream);

  // K0: converts + transposes
  conv_f32_bf16_x4<<<4096, 256, 0, stream>>>(embed, embB, 1048576);
  transpose_conv<<<dim3(32, 32),  dim3(32, 8), 0, stream>>>(Wc,                WxT, 1024, 1024);
  transpose_conv<<<dim3(32, 32),  dim3(32, 8), 0, stream>>>(Wc + 1024 * 1024,  WrT, 1024, 1024);
  transpose_conv<<<dim3(128, 32), dim3(32, 8), 0, stream>>>(Wh,                WhT, 1024, 4096);

  // K1: xp = embed[input] @ Wx + bc   (f32 out)
  gemm_bf16<true, false><<<dim3(256, 8), 256, 0, stream>>>(
      embB, input, WxT, bc, (void*)xp, 32768, 1024, 1024);

  // K2: recurrence (cooperative launch for guaranteed co-residency; custom barriers)
  {
    const float* xp_c = xp;
    const short* WrT_c = WrT;
    const float* h0_c = h0;
    short* hs_c = hs;
    unsigned int* bar_c = bar;
    void* args[] = {(void*)&xp_c, (void*)&WrT_c, (void*)&h0_c, (void*)&hs_c, (void*)&bar_c};
    hipLaunchCooperativeKernel((const void*)rnn_recur, dim3(64), dim3(256), args, 0, stream);
  }

  // K3: out = hs @ Wh + bh  (f32 out)
  gemm_bf16<false, false><<<dim3(256, 32), 256, 0, stream>>>(
      hs, nullptr, WhT, bh, d_out, 32768, 4096, 1024);
}

// Round 6
// 3618.059 us; speedup vs baseline: 1.3073x; 1.3073x over previous
//
#include <hip/hip_runtime.h>
#include <hip/hip_bf16.h>
#include <hip/hip_cooperative_groups.h>
#include <cstddef>

typedef short bf16x8 __attribute__((ext_vector_type(8)));
typedef float f32x4 __attribute__((ext_vector_type(4)));

// Constants for this problem: V=4096, D=1024, H=1024, B=64, T=512

__device__ __forceinline__ short bf16rne(float f) {
  unsigned u = __builtin_bit_cast(unsigned, f);
  u += 0x7fffu + ((u >> 16) & 1u);
  return (short)(u >> 16);
}

// Inline tanh (no ocml call: a call forces caller-saved spills of wfrag).
// tanh(x) = 1 - 2/(exp(2x)+1); exp(2x) = exp2(x * 2*log2(e)). ~1ulp, bf16-fine.
__device__ __forceinline__ float fast_tanh(float x) {
  float e = __builtin_amdgcn_exp2f(x * 2.88539008177792681f);
  return 1.0f - 2.0f * __builtin_amdgcn_rcpf(e + 1.0f);
}

// ---------------- K0a: elementwise f32 -> bf16 convert (x4 per thread) ----------------
__global__ void conv_f32_bf16_x4(const float* __restrict__ src, short* __restrict__ dst, int n4) {
  int i = blockIdx.x * blockDim.x + threadIdx.x;
  if (i >= n4) return;
  float4 v = ((const float4*)src)[i];
  unsigned long long o =
      (unsigned long long)(unsigned short)bf16rne(v.x) |
      ((unsigned long long)(unsigned short)bf16rne(v.y) << 16) |
      ((unsigned long long)(unsigned short)bf16rne(v.z) << 32) |
      ((unsigned long long)(unsigned short)bf16rne(v.w) << 48);
  ((unsigned long long*)dst)[i] = o;
}

// ---------------- K0b: tiled transpose + convert: dst[c][r] = bf16(src[r][c]) ----------------
__global__ void transpose_conv(const float* __restrict__ src, short* __restrict__ dst,
                               int R, int C) {
  __shared__ float tile[32][33];
  int tx = threadIdx.x, ty = threadIdx.y;
  int bx = blockIdx.x, by = blockIdx.y;
#pragma unroll
  for (int i = 0; i < 4; ++i)
    tile[ty + i * 8][tx] = src[(size_t)(by * 32 + ty + i * 8) * C + bx * 32 + tx];
  __syncthreads();
#pragma unroll
  for (int i = 0; i < 4; ++i)
    dst[(size_t)(bx * 32 + ty + i * 8) * R + by * 32 + tx] = bf16rne(tile[tx][ty + i * 8]);
}

// ---------------- K1/K3: 128x128 tile MFMA GEMM, BK=32, 4 waves (2x2 of 64x64) ----------------
template <bool GATHER, bool OUT_BF16>
__global__ __launch_bounds__(256) void gemm_bf16(
    const short* __restrict__ Abase, const int* __restrict__ gidx,
    const short* __restrict__ BT, const float* __restrict__ bias,
    void* __restrict__ Cout, int M, int N, int K) {
  __shared__ short As[128][40];
  __shared__ short Bs[128][40];
  const int tid = threadIdx.x;
  const int lane = tid & 63;
  const int wave = tid >> 6;
  const int mbase = blockIdx.x * 128;
  const int nbase = blockIdx.y * 128;
  const int wr = (wave >> 1) * 64;
  const int wc = (wave & 1) * 64;
  const int l15 = lane & 15;
  const int lk8 = (lane >> 4) * 8;
  const int r0 = tid >> 2;
  const int kc = (tid & 3) * 8;

  f32x4 acc[4][4] = {};

  for (int k0 = 0; k0 < K; k0 += 32) {
#pragma unroll
    for (int h = 0; h < 2; ++h) {
      int r = r0 + h * 64;
      size_t arow;
      if (GATHER) arow = (size_t)gidx[mbase + r];
      else        arow = (size_t)(mbase + r);
      *(bf16x8*)&As[r][kc] = *(const bf16x8*)(Abase + arow * (size_t)K + k0 + kc);
      *(bf16x8*)&Bs[r][kc] = *(const bf16x8*)(BT + (size_t)(nbase + r) * K + k0 + kc);
    }
    __syncthreads();
    bf16x8 af[4], bfr[4];
#pragma unroll
    for (int i = 0; i < 4; ++i) {
      af[i]  = *(const bf16x8*)&As[wr + i * 16 + l15][lk8];
      bfr[i] = *(const bf16x8*)&Bs[wc + i * 16 + l15][lk8];
    }
#pragma unroll
    for (int i = 0; i < 4; ++i)
#pragma unroll
      for (int j = 0; j < 4; ++j)
        acc[i][j] = __builtin_amdgcn_mfma_f32_16x16x32_bf16(af[i], bfr[j], acc[i][j], 0, 0, 0);
    __syncthreads();
  }

#pragma unroll
  for (int i = 0; i < 4; ++i)
#pragma unroll
    for (int j = 0; j < 4; ++j) {
      int col = nbase + wc + j * 16 + l15;
      float bv = bias ? bias[col] : 0.f;
#pragma unroll
      for (int r = 0; r < 4; ++r) {
        int row = mbase + wr + i * 16 + (lane >> 4) * 4 + r;
        float v = acc[i][j][r] + bv;
        if (OUT_BF16) ((short*)Cout)[(size_t)row * N + col] = bf16rne(v);
        else          ((float*)Cout)[(size_t)row * N + col] = v;
      }
    }
}

// ---------------- K2: recurrence ----------------
// 64 blocks x 256 threads; rg = bid>>4 owns batches [rg*16, rg*16+16); the 16
// col-blocks of a rowgroup sync via a monotone IF-resident counter.
// Protocol (R4-proven pieces only):
//   release: sc1 write-through h-stores -> s_waitcnt vmcnt(0) -> syncthreads
//            -> tid0 atomicAdd (device scope, lands at IF after the drain).
//   acquire: all waves spin on relaxed agent load (sc1, reads IF); compiler
//            memory barrier stops load hoisting; h_{t-1} addresses were never
//            cached by the consumer -> cached loads miss to IF -> fresh.
// No buffer_inv, no buffer_wbl2 anywhere; WrT/xp stay hot in L1/L2.
__global__ __launch_bounds__(256, 1) void rnn_recur(
    const float* __restrict__ xp, const short* __restrict__ WrT,
    const float* __restrict__ h0, short* __restrict__ hs,
    unsigned int* __restrict__ bar) {
  const int tid = threadIdx.x;
  const int lane = tid & 63;
  const int wave = tid >> 6;
  const int bid = blockIdx.x;
  const int rg = bid >> 4;
  const int rowbase = rg * 16;
  const int colbase = (bid & 15) * 64 + wave * 16;
  const int l15 = lane & 15;
  const int lk8 = (lane >> 4) * 8;
  const int col = colbase + l15;
  unsigned int* cnt = bar + rg * 256;  // 1 KB apart per rowgroup

  // Preload Wr B-fragments for this wave's 16 columns (32 x bf16x8 = 128 VGPRs).
  bf16x8 wfrag[32];
#pragma unroll
  for (int ks = 0; ks < 32; ++ks)
    wfrag[ks] = *(const bf16x8*)(WrT + (size_t)col * 1024 + ks * 32 + lk8);

  const int rquad = (lane >> 4) * 4;  // first of this thread's 4 output rows

  // ---- t = 0: previous h is h0 (broadcast row) ----
  {
    f32x4 a0 = {}, a1 = {}, a2 = {}, a3 = {};
#pragma unroll
    for (int ks = 0; ks < 32; ks += 4) {
      bf16x8 a[4];
#pragma unroll
      for (int q = 0; q < 4; ++q) {
        const float* hp = h0 + (ks + q) * 32 + lk8;
#pragma unroll
        for (int j = 0; j < 8; ++j) a[q][j] = bf16rne(hp[j]);
      }
      a0 = __builtin_amdgcn_mfma_f32_16x16x32_bf16(a[0], wfrag[ks + 0], a0, 0, 0, 0);
      a1 = __builtin_amdgcn_mfma_f32_16x16x32_bf16(a[1], wfrag[ks + 1], a1, 0, 0, 0);
      a2 = __builtin_amdgcn_mfma_f32_16x16x32_bf16(a[2], wfrag[ks + 2], a2, 0, 0, 0);
      a3 = __builtin_amdgcn_mfma_f32_16x16x32_bf16(a[3], wfrag[ks + 3], a3, 0, 0, 0);
    }
    f32x4 acc = (a0 + a1) + (a2 + a3);
#pragma unroll
    for (int r = 0; r < 4; ++r) {
      int b = rowbase + rquad + r;
      size_t off = ((size_t)b * 512 + 0) * 1024 + col;
      short hv = bf16rne(fast_tanh(acc[r] + xp[off]));
      __hip_atomic_store(&hs[off], hv, __ATOMIC_RELAXED, __HIP_MEMORY_SCOPE_AGENT);
    }
  }

  // prefetch xp for t = 1
  float xv[4];
#pragma unroll
  for (int r = 0; r < 4; ++r)
    xv[r] = xp[((size_t)(rowbase + rquad + r) * 512 + 1) * 1024 + col];

  for (int t = 1; t < 512; ++t) {
    // prefetch xp for t+1 (static data, race-free) — completes while we sync
    const int tn = (t + 1 < 512) ? (t + 1) : 511;
    float xn[4];
#pragma unroll
    for (int r = 0; r < 4; ++r)
      xn[r] = xp[((size_t)(rowbase + rquad + r) * 512 + tn) * 1024 + col];

    // release: drain own sc1 h-stores (now at IF), block-wide join, then arrive
    asm volatile("s_waitcnt vmcnt(0)" ::: "memory");
    __syncthreads();
    if (tid == 0) atomicAdd(cnt, 1u);

    // acquire: every wave spins until all 16 blocks of this rowgroup posted
    const unsigned target = 16u * (unsigned)t;
    while (__hip_atomic_load(cnt, __ATOMIC_RELAXED, __HIP_MEMORY_SCOPE_AGENT) < target) {}
    asm volatile("" ::: "memory");  // no static hoist of h loads above the spin

    // h_{t-1} @ Wr with 4 independent accumulator chains (cached loads; the
    // addresses are new this step -> L2 miss -> fresh from IF)
    f32x4 a0 = {}, a1 = {}, a2 = {}, a3 = {};
    const short* hrow = hs + ((size_t)(rowbase + l15) * 512 + (t - 1)) * 1024 + lk8;
#pragma unroll
    for (int ks = 0; ks < 32; ks += 4) {
      bf16x8 a[4];
#pragma unroll
      for (int q = 0; q < 4; ++q)
        a[q] = *(const bf16x8*)(hrow + (ks + q) * 32);
      a0 = __builtin_amdgcn_mfma_f32_16x16x32_bf16(a[0], wfrag[ks + 0], a0, 0, 0, 0);
      a1 = __builtin_amdgcn_mfma_f32_16x16x32_bf16(a[1], wfrag[ks + 1], a1, 0, 0, 0);
      a2 = __builtin_amdgcn_mfma_f32_16x16x32_bf16(a[2], wfrag[ks + 2], a2, 0, 0, 0);
      a3 = __builtin_amdgcn_mfma_f32_16x16x32_bf16(a[3], wfrag[ks + 3], a3, 0, 0, 0);
    }
    f32x4 acc = (a0 + a1) + (a2 + a3);

#pragma unroll
    for (int r = 0; r < 4; ++r) {
      int b = rowbase + rquad + r;
      size_t off = ((size_t)b * 512 + t) * 1024 + col;
      short hv = bf16rne(fast_tanh(acc[r] + xv[r]));
      __hip_atomic_store(&hs[off], hv, __ATOMIC_RELAXED, __HIP_MEMORY_SCOPE_AGENT);
    }
#pragma unroll
    for (int r = 0; r < 4; ++r) xv[r] = xn[r];
  }
}

// ---------------- launch ----------------
extern "C" void kernel_launch(void* const* d_in, const int* in_sizes, int n_in,
                              void* d_out, int out_size, void* d_ws, size_t ws_size,
                              hipStream_t stream) {
  const int*   input = (const int*)d_in[0];    // [B][T] = [64][512]
  const float* embed = (const float*)d_in[1];  // [V][D] = [4096][1024]
  const float* Wc    = (const float*)d_in[2];  // [D+H][H] = [2048][1024]
  const float* bc    = (const float*)d_in[3];  // [H]
  const float* h0    = (const float*)d_in[4];  // [1][H]
  const float* Wh    = (const float*)d_in[5];  // [H][V] = [1024][4096]
  const float* bh    = (const float*)d_in[6];  // [V]

  char* ws = (char*)d_ws;
  float* xp   = (float*)(ws + 0);            // 32768*1024 f32  = 134,217,728 B
  short* hs   = (short*)(ws + 134217728);    // 32768*1024 bf16 =  67,108,864 B
  short* embB = (short*)(ws + 201326592);    // 4096*1024 bf16  =   8,388,608 B
  short* WxT  = (short*)(ws + 209715200);    // 1024*1024 bf16  =   2,097,152 B
  short* WrT  = (short*)(ws + 211812352);    // 1024*1024 bf16  =   2,097,152 B
  short* WhT  = (short*)(ws + 213909504);    // 4096*1024 bf16  =   8,388,608 B
  unsigned int* bar = (unsigned int*)(ws + 222298112);  // 4 KB barrier counters

  hipMemsetAsync(bar, 0, 4096, stream);

  // K0: converts + transposes
  conv_f32_bf16_x4<<<4096, 256, 0, stream>>>(embed, embB, 1048576);
  transpose_conv<<<dim3(32, 32),  dim3(32, 8), 0, stream>>>(Wc,                WxT, 1024, 1024);
  transpose_conv<<<dim3(32, 32),  dim3(32, 8), 0, stream>>>(Wc + 1024 * 1024,  WrT, 1024, 1024);
  transpose_conv<<<dim3(128, 32), dim3(32, 8), 0, stream>>>(Wh,                WhT, 1024, 4096);

  // K1: xp = embed[input] @ Wx + bc   (f32 out)
  gemm_bf16<true, false><<<dim3(256, 8), 256, 0, stream>>>(
      embB, input, WxT, bc, (void*)xp, 32768, 1024, 1024);

  // K2: recurrence (cooperative launch for guaranteed co-residency; custom barriers)
  {
    const float* xp_c = xp;
    const short* WrT_c = WrT;
    const float* h0_c = h0;
    short* hs_c = hs;
    unsigned int* bar_c = bar;
    void* args[] = {(void*)&xp_c, (void*)&WrT_c, (void*)&h0_c, (void*)&hs_c, (void*)&bar_c};
    hipLaunchCooperativeKernel((const void*)rnn_recur, dim3(64), dim3(256), args, 0, stream);
  }

  // K3: out = hs @ Wh + bh  (f32 out)
  gemm_bf16<false, false><<<dim3(256, 32), 256, 0, stream>>>(
      hs, nullptr, WhT, bh, d_out, 32768, 4096, 1024);
}

// Round 7
// 3271.832 us; speedup vs baseline: 1.4457x; 1.1058x over previous
//
#include <hip/hip_runtime.h>
#include <hip/hip_bf16.h>
#include <hip/hip_cooperative_groups.h>
#include <cstddef>

typedef short bf16x8 __attribute__((ext_vector_type(8)));
typedef float f32x4 __attribute__((ext_vector_type(4)));

// Constants for this problem: V=4096, D=1024, H=1024, B=64, T=512

__device__ __forceinline__ short bf16rne(float f) {
  unsigned u = __builtin_bit_cast(unsigned, f);
  u += 0x7fffu + ((u >> 16) & 1u);
  return (short)(u >> 16);
}

// Inline tanh (no ocml call: a call forces caller-saved spills of wfrag).
// tanh(x) = 1 - 2/(exp(2x)+1); exp(2x) = exp2(x * 2*log2(e)). ~1ulp, bf16-fine.
__device__ __forceinline__ float fast_tanh(float x) {
  float e = __builtin_amdgcn_exp2f(x * 2.88539008177792681f);
  return 1.0f - 2.0f * __builtin_amdgcn_rcpf(e + 1.0f);
}

// ---------------- K0a: elementwise f32 -> bf16 convert (x4 per thread) ----------------
__global__ void conv_f32_bf16_x4(const float* __restrict__ src, short* __restrict__ dst, int n4) {
  int i = blockIdx.x * blockDim.x + threadIdx.x;
  if (i >= n4) return;
  float4 v = ((const float4*)src)[i];
  unsigned long long o =
      (unsigned long long)(unsigned short)bf16rne(v.x) |
      ((unsigned long long)(unsigned short)bf16rne(v.y) << 16) |
      ((unsigned long long)(unsigned short)bf16rne(v.z) << 32) |
      ((unsigned long long)(unsigned short)bf16rne(v.w) << 48);
  ((unsigned long long*)dst)[i] = o;
}

// ---------------- K0b: tiled transpose + convert: dst[c][r] = bf16(src[r][c]) ----------------
__global__ void transpose_conv(const float* __restrict__ src, short* __restrict__ dst,
                               int R, int C) {
  __shared__ float tile[32][33];
  int tx = threadIdx.x, ty = threadIdx.y;
  int bx = blockIdx.x, by = blockIdx.y;
#pragma unroll
  for (int i = 0; i < 4; ++i)
    tile[ty + i * 8][tx] = src[(size_t)(by * 32 + ty + i * 8) * C + bx * 32 + tx];
  __syncthreads();
#pragma unroll
  for (int i = 0; i < 4; ++i)
    dst[(size_t)(bx * 32 + ty + i * 8) * R + by * 32 + tx] = bf16rne(tile[tx][ty + i * 8]);
}

// ---------------- K1/K3: 128x128 tile MFMA GEMM, BK=32, 4 waves (2x2 of 64x64) ----------------
template <bool GATHER, bool OUT_BF16>
__global__ __launch_bounds__(256) void gemm_bf16(
    const short* __restrict__ Abase, const int* __restrict__ gidx,
    const short* __restrict__ BT, const float* __restrict__ bias,
    void* __restrict__ Cout, int M, int N, int K) {
  __shared__ short As[128][40];
  __shared__ short Bs[128][40];
  const int tid = threadIdx.x;
  const int lane = tid & 63;
  const int wave = tid >> 6;
  const int mbase = blockIdx.x * 128;
  const int nbase = blockIdx.y * 128;
  const int wr = (wave >> 1) * 64;
  const int wc = (wave & 1) * 64;
  const int l15 = lane & 15;
  const int lk8 = (lane >> 4) * 8;
  const int r0 = tid >> 2;
  const int kc = (tid & 3) * 8;

  f32x4 acc[4][4] = {};

  for (int k0 = 0; k0 < K; k0 += 32) {
#pragma unroll
    for (int h = 0; h < 2; ++h) {
      int r = r0 + h * 64;
      size_t arow;
      if (GATHER) arow = (size_t)gidx[mbase + r];
      else        arow = (size_t)(mbase + r);
      *(bf16x8*)&As[r][kc] = *(const bf16x8*)(Abase + arow * (size_t)K + k0 + kc);
      *(bf16x8*)&Bs[r][kc] = *(const bf16x8*)(BT + (size_t)(nbase + r) * K + k0 + kc);
    }
    __syncthreads();
    bf16x8 af[4], bfr[4];
#pragma unroll
    for (int i = 0; i < 4; ++i) {
      af[i]  = *(const bf16x8*)&As[wr + i * 16 + l15][lk8];
      bfr[i] = *(const bf16x8*)&Bs[wc + i * 16 + l15][lk8];
    }
#pragma unroll
    for (int i = 0; i < 4; ++i)
#pragma unroll
      for (int j = 0; j < 4; ++j)
        acc[i][j] = __builtin_amdgcn_mfma_f32_16x16x32_bf16(af[i], bfr[j], acc[i][j], 0, 0, 0);
    __syncthreads();
  }

#pragma unroll
  for (int i = 0; i < 4; ++i)
#pragma unroll
    for (int j = 0; j < 4; ++j) {
      int col = nbase + wc + j * 16 + l15;
      float bv = bias ? bias[col] : 0.f;
#pragma unroll
      for (int r = 0; r < 4; ++r) {
        int row = mbase + wr + i * 16 + (lane >> 4) * 4 + r;
        float v = acc[i][j][r] + bv;
        if (OUT_BF16) ((short*)Cout)[(size_t)row * N + col] = bf16rne(v);
        else          ((float*)Cout)[(size_t)row * N + col] = v;
      }
    }
}

// ---------------- K2: recurrence ----------------
// 64 blocks x 256 threads; rg = bid>>4 owns batches [rg*16, rg*16+16); the 16
// col-blocks of a rowgroup sync via a monotone IF-resident counter.
// Protocol (R6-proven):
//   release: sc1 write-through h-stores -> s_waitcnt vmcnt(0) -> s_barrier
//            -> tid0 atomicAdd (agent scope, at IF).
//   acquire: wave0 spins (coalesced, s_sleep backoff); s_barrier releases the
//            block; h_{t-1} addresses were never cached by the consumer ->
//            cached loads miss to IF -> fresh.
// Wr fragments: loaded ONCE via volatile loads (cannot be rematerialized ->
// must stay in VGPRs all 512 steps).
// xp prefetch for t+1 is issued between arrive and spin so it flies during
// the wait instead of delaying the arrival.
__global__ __launch_bounds__(256, 1) void rnn_recur(
    const float* __restrict__ xp, const short* __restrict__ WrT,
    const float* __restrict__ h0, short* __restrict__ hs,
    unsigned int* __restrict__ bar) {
  const int tid = threadIdx.x;
  const int lane = tid & 63;
  const int wave = tid >> 6;
  const int bid = blockIdx.x;
  const int rg = bid >> 4;
  const int rowbase = rg * 16;
  const int colbase = (bid & 15) * 64 + wave * 16;
  const int l15 = lane & 15;
  const int lk8 = (lane >> 4) * 8;
  const int col = colbase + l15;
  unsigned int* cnt = bar + rg * 256;  // 1 KB apart per rowgroup

  // Preload Wr B-fragments (32 x bf16x8 = 128 VGPRs) with VOLATILE loads:
  // volatile loads cannot be re-executed, so regalloc must keep the values
  // resident instead of rematerializing the loads inside the loop.
  bf16x8 wfrag[32];
#pragma unroll
  for (int ks = 0; ks < 32; ++ks)
    wfrag[ks] = *(const volatile bf16x8*)(WrT + (size_t)col * 1024 + ks * 32 + lk8);

  const int rquad = (lane >> 4) * 4;  // first of this thread's 4 output rows

  // ---- t = 0: previous h is h0 (broadcast row) ----
  {
    f32x4 a0 = {}, a1 = {}, a2 = {}, a3 = {};
#pragma unroll
    for (int ks = 0; ks < 32; ks += 4) {
      bf16x8 a[4];
#pragma unroll
      for (int q = 0; q < 4; ++q) {
        const float* hp = h0 + (ks + q) * 32 + lk8;
#pragma unroll
        for (int j = 0; j < 8; ++j) a[q][j] = bf16rne(hp[j]);
      }
      a0 = __builtin_amdgcn_mfma_f32_16x16x32_bf16(a[0], wfrag[ks + 0], a0, 0, 0, 0);
      a1 = __builtin_amdgcn_mfma_f32_16x16x32_bf16(a[1], wfrag[ks + 1], a1, 0, 0, 0);
      a2 = __builtin_amdgcn_mfma_f32_16x16x32_bf16(a[2], wfrag[ks + 2], a2, 0, 0, 0);
      a3 = __builtin_amdgcn_mfma_f32_16x16x32_bf16(a[3], wfrag[ks + 3], a3, 0, 0, 0);
    }
    f32x4 acc = (a0 + a1) + (a2 + a3);
#pragma unroll
    for (int r = 0; r < 4; ++r) {
      int b = rowbase + rquad + r;
      size_t off = ((size_t)b * 512 + 0) * 1024 + col;
      short hv = bf16rne(fast_tanh(acc[r] + xp[off]));
      __hip_atomic_store(&hs[off], hv, __ATOMIC_RELAXED, __HIP_MEMORY_SCOPE_AGENT);
    }
  }

  // prefetch xp for t = 1
  float xv[4];
#pragma unroll
  for (int r = 0; r < 4; ++r)
    xv[r] = xp[((size_t)(rowbase + rquad + r) * 512 + 1) * 1024 + col];

  for (int t = 1; t < 512; ++t) {
    // release: every wave drains its own sc1 h-stores (now at IF), then
    // block-wide raw barrier, then tid0 arrives at the rowgroup counter
    asm volatile("s_waitcnt vmcnt(0)" ::: "memory");
    __builtin_amdgcn_s_barrier();
    if (tid == 0) atomicAdd(cnt, 1u);

    // prefetch xp for t+1 NOW — it completes while we wait for peers
    const int tn = (t + 1 < 512) ? (t + 1) : 511;
    float xn[4];
#pragma unroll
    for (int r = 0; r < 4; ++r)
      xn[r] = xp[((size_t)(rowbase + rquad + r) * 512 + tn) * 1024 + col];

    // acquire: wave0 spins (one coalesced IF transaction per poll per block)
    if (wave == 0) {
      const unsigned target = 16u * (unsigned)t;
      while (__hip_atomic_load(cnt, __ATOMIC_RELAXED, __HIP_MEMORY_SCOPE_AGENT) < target)
        __builtin_amdgcn_s_sleep(1);
    }
    __builtin_amdgcn_s_barrier();
    asm volatile("" ::: "memory");        // no static hoist of h loads above
    __builtin_amdgcn_sched_barrier(0);    // rule 18: pin ordering

    // h_{t-1} @ Wr with 4 independent accumulator chains (cached loads; the
    // addresses are new this step -> L2 miss -> fresh from IF)
    f32x4 a0 = {}, a1 = {}, a2 = {}, a3 = {};
    const short* hrow = hs + ((size_t)(rowbase + l15) * 512 + (t - 1)) * 1024 + lk8;
#pragma unroll
    for (int ks = 0; ks < 32; ks += 4) {
      bf16x8 a[4];
#pragma unroll
      for (int q = 0; q < 4; ++q)
        a[q] = *(const bf16x8*)(hrow + (ks + q) * 32);
      a0 = __builtin_amdgcn_mfma_f32_16x16x32_bf16(a[0], wfrag[ks + 0], a0, 0, 0, 0);
      a1 = __builtin_amdgcn_mfma_f32_16x16x32_bf16(a[1], wfrag[ks + 1], a1, 0, 0, 0);
      a2 = __builtin_amdgcn_mfma_f32_16x16x32_bf16(a[2], wfrag[ks + 2], a2, 0, 0, 0);
      a3 = __builtin_amdgcn_mfma_f32_16x16x32_bf16(a[3], wfrag[ks + 3], a3, 0, 0, 0);
    }
    f32x4 acc = (a0 + a1) + (a2 + a3);

#pragma unroll
    for (int r = 0; r < 4; ++r) {
      int b = rowbase + rquad + r;
      size_t off = ((size_t)b * 512 + t) * 1024 + col;
      short hv = bf16rne(fast_tanh(acc[r] + xv[r]));
      __hip_atomic_store(&hs[off], hv, __ATOMIC_RELAXED, __HIP_MEMORY_SCOPE_AGENT);
    }
#pragma unroll
    for (int r = 0; r < 4; ++r) xv[r] = xn[r];
  }
}

// ---------------- launch ----------------
extern "C" void kernel_launch(void* const* d_in, const int* in_sizes, int n_in,
                              void* d_out, int out_size, void* d_ws, size_t ws_size,
                              hipStream_t stream) {
  const int*   input = (const int*)d_in[0];    // [B][T] = [64][512]
  const float* embed = (const float*)d_in[1];  // [V][D] = [4096][1024]
  const float* Wc    = (const float*)d_in[2];  // [D+H][H] = [2048][1024]
  const float* bc    = (const float*)d_in[3];  // [H]
  const float* h0    = (const float*)d_in[4];  // [1][H]
  const float* Wh    = (const float*)d_in[5];  // [H][V] = [1024][4096]
  const float* bh    = (const float*)d_in[6];  // [V]

  char* ws = (char*)d_ws;
  float* xp   = (float*)(ws + 0);            // 32768*1024 f32  = 134,217,728 B
  short* hs   = (short*)(ws + 134217728);    // 32768*1024 bf16 =  67,108,864 B
  short* embB = (short*)(ws + 201326592);    // 4096*1024 bf16  =   8,388,608 B
  short* WxT  = (short*)(ws + 209715200);    // 1024*1024 bf16  =   2,097,152 B
  short* WrT  = (short*)(ws + 211812352);    // 1024*1024 bf16  =   2,097,152 B
  short* WhT  = (short*)(ws + 213909504);    // 4096*1024 bf16  =   8,388,608 B
  unsigned int* bar = (unsigned int*)(ws + 222298112);  // 4 KB barrier counters

  hipMemsetAsync(bar, 0, 4096, stream);

  // K0: converts + transposes
  conv_f32_bf16_x4<<<4096, 256, 0, stream>>>(embed, embB, 1048576);
  transpose_conv<<<dim3(32, 32),  dim3(32, 8), 0, stream>>>(Wc,                WxT, 1024, 1024);
  transpose_conv<<<dim3(32, 32),  dim3(32, 8), 0, stream>>>(Wc + 1024 * 1024,  WrT, 1024, 1024);
  transpose_conv<<<dim3(128, 32), dim3(32, 8), 0, stream>>>(Wh,                WhT, 1024, 4096);

  // K1: xp = embed[input] @ Wx + bc   (f32 out)
  gemm_bf16<true, false><<<dim3(256, 8), 256, 0, stream>>>(
      embB, input, WxT, bc, (void*)xp, 32768, 1024, 1024);

  // K2: recurrence (cooperative launch for guaranteed co-residency; custom barriers)
  {
    const float* xp_c = xp;
    const short* WrT_c = WrT;
    const float* h0_c = h0;
    short* hs_c = hs;
    unsigned int* bar_c = bar;
    void* args[] = {(void*)&xp_c, (void*)&WrT_c, (void*)&h0_c, (void*)&hs_c, (void*)&bar_c};
    hipLaunchCooperativeKernel((const void*)rnn_recur, dim3(64), dim3(256), args, 0, stream);
  }

  // K3: out = hs @ Wh + bh  (f32 out)
  gemm_bf16<false, false><<<dim3(256, 32), 256, 0, stream>>>(
      hs, nullptr, WhT, bh, d_out, 32768, 4096, 1024);
}